// Round 6
// baseline (429.205 us; speedup 1.0000x reference)
//
#include <hip/hip_runtime.h>
#include <stdint.h>

// ---- problem constants ----
#define NPATCH 3136      // 64 images * 49 patches
#define MPAD   3328      // 13 * 256
#define NBANK  100000
#define NBPAD  100096    // 391 * 256
#define DIM    768
#define BM 256
#define BN 256
#define BK 128              // int8 K-tile (128 B rows)
#define KTILES (DIM / BK)   // 6
#define MT 13               // MPAD / BM
#define NT 391              // NBPAD / BN
#define ABYTES (BM * BK)    // 32 KB
#define BBYTES (BN * BK)    // 32 KB

typedef __attribute__((ext_vector_type(4))) float f32x4;
typedef __attribute__((ext_vector_type(4))) int   i32x4;

// monotonic float<->uint mapping for atomicMax on floats (incl. negatives)
__device__ __forceinline__ unsigned fkey(float f) {
    unsigned u = __float_as_uint(f);
    return (u & 0x80000000u) ? ~u : (u | 0x80000000u);
}
__device__ __forceinline__ float funkey(unsigned u) {
    return __uint_as_float((u & 0x80000000u) ? (u ^ 0x80000000u) : ~u);
}

// ---- kernel 0: zero the per-patch max-key buffer ----
__global__ void k_init(unsigned* __restrict__ keys) {
    int i = blockIdx.x * 256 + threadIdx.x;
    if (i < MPAD) keys[i] = 0u;
}

// ---- shared: quantize one 768-float row to int8 with scale sa = vmax/(127*(||a||+eps))
__device__ __forceinline__ void quant_row(const float* __restrict__ src,
                                          signed char* __restrict__ dst,
                                          float* __restrict__ sa_p, int lane) {
    f32x4 v[3];
    float ss = 0.f, vm = 0.f;
#pragma unroll
    for (int i = 0; i < 3; i++) {
        v[i] = ((const f32x4*)src)[lane + 64 * i];
#pragma unroll
        for (int c = 0; c < 4; c++) {
            ss += v[i][c] * v[i][c];
            vm = fmaxf(vm, fabsf(v[i][c]));
        }
    }
#pragma unroll
    for (int d = 1; d < 64; d <<= 1) {
        ss += __shfl_xor(ss, d);
        vm = fmaxf(vm, __shfl_xor(vm, d));
    }
    float k = (vm > 0.f) ? 127.0f / vm : 0.f;
#pragma unroll
    for (int i = 0; i < 3; i++) {
        char4 o;
        o.x = (signed char)__float2int_rn(v[i][0] * k);
        o.y = (signed char)__float2int_rn(v[i][1] * k);
        o.z = (signed char)__float2int_rn(v[i][2] * k);
        o.w = (signed char)__float2int_rn(v[i][3] * k);
        ((char4*)dst)[lane + 64 * i] = o;
    }
    if (lane == 0) *sa_p = vm / (127.0f * (sqrtf(ss) + 1e-12f));
}

__device__ __forceinline__ void zero_row(signed char* __restrict__ dst,
                                         float* __restrict__ sa_p, int lane) {
    char4 z; z.x = z.y = z.z = z.w = 0;
#pragma unroll
    for (int i = 0; i < 3; i++) ((char4*)dst)[lane + 64 * i] = z;
    if (lane == 0) *sa_p = 0.f;
}

// ---- kernel 1: patches (drop CLS) -> int8 A[MPAD][DIM] + sa[MPAD] ----
__global__ void k_q8a(const float* __restrict__ tokens, signed char* __restrict__ A,
                      float* __restrict__ sa) {
    int wv = threadIdx.x >> 6, lane = threadIdx.x & 63;
    int r = blockIdx.x * 4 + wv;
    if (r >= MPAD) return;
    signed char* dst = A + (size_t)r * DIM;
    if (r >= NPATCH) { zero_row(dst, sa + r, lane); return; }
    int b = r / 49, j = r % 49;
    const float* src = tokens + (size_t)(b * 50 + 1 + j) * DIM;  // skip CLS
    quant_row(src, dst, sa + r, lane);
}

// ---- kernel 2: bank -> int8 Bq[NBPAD][DIM] + sb[NBPAD] ----
__global__ void k_q8b(const float* __restrict__ mb, signed char* __restrict__ Bq,
                      float* __restrict__ sb) {
    int wv = threadIdx.x >> 6, lane = threadIdx.x & 63;
    int r = blockIdx.x * 4 + wv;
    if (r >= NBPAD) return;
    signed char* dst = Bq + (size_t)r * DIM;
    if (r >= NBANK) { zero_row(dst, sb + r, lane); return; }
    quant_row(mb + (size_t)r * DIM, dst, sb + r, lane);
}

// ---- kernel 3: int8 MFMA GEMM, 256x256 tile, 8 waves of 128x64,
//      m201-style 4-phase-per-K-tile schedule: per phase
//      {8 ds_read_b128 | 4 DMA stage} -> barrier -> lgkmcnt(0) -> 16 MFMA -> barrier.
// LDS rows are 128 B = 8 chunks of 16 B; slot c holds global chunk c^(row&7).
// global_load_lds dest stays LINEAR (rule #21); the SOURCE chunk is permuted.
__global__ void __launch_bounds__(512, 1) k_gemm(const signed char* __restrict__ A,
                                                 const signed char* __restrict__ Bq,
                                                 const float* __restrict__ sb,
                                                 unsigned* __restrict__ keys) {
    __shared__ __align__(16) signed char lds[2][ABYTES + BBYTES];   // 128 KB

    // T1: bijective XCD swizzle (m204; nwg=5083, nwg%8=3)
    const int nwg = MT * NT;
    const int q = nwg >> 3, r8 = nwg & 7;
    const int xcd = blockIdx.x & 7, loc = blockIdx.x >> 3;
    const int wg = (xcd < r8 ? xcd * (q + 1) : r8 * (q + 1) + (xcd - r8) * q) + loc;
    const int mt = wg % MT;          // m-fastest within an XCD: 13 blocks share one B tile
    const int nt = wg / MT;

    const int t = threadIdx.x;
    const int lane = t & 63, wv = t >> 6;

    const signed char* Ab = A + (size_t)(mt * BM) * DIM;
    const signed char* Bb = Bq + (size_t)(nt * BN) * DIM;

    // A: 2048 16B chunks, 4 per thread; same for B.
    auto stageA4 = [&](int buf, int kt) {
#pragma unroll
        for (int it = 0; it < 4; it++) {
            int id = it * 512 + t;
            int row = id >> 3, cs = id & 7;            // linear LDS slot
            const signed char* g = Ab + (size_t)row * DIM + kt * BK + ((cs ^ (row & 7)) << 4);
            __builtin_amdgcn_global_load_lds(
                (const __attribute__((address_space(1))) unsigned int*)g,
                (__attribute__((address_space(3))) unsigned int*)(&lds[buf][id * 16]), 16, 0, 0);
        }
    };
    auto stageB4 = [&](int buf, int kt) {
#pragma unroll
        for (int it = 0; it < 4; it++) {
            int id = it * 512 + t;
            int row = id >> 3, cs = id & 7;
            const signed char* g = Bb + (size_t)row * DIM + kt * BK + ((cs ^ (row & 7)) << 4);
            __builtin_amdgcn_global_load_lds(
                (const __attribute__((address_space(1))) unsigned int*)g,
                (__attribute__((address_space(3))) unsigned int*)(&lds[buf][ABYTES + id * 16]), 16, 0, 0);
        }
    };

    // wave -> 128x64 output tile; wave grid 2M x 4N over 256x256
    i32x4 acc[8][4] = {};
    const int wm = (wv >> 2) * 128;    // 0 or 128
    const int wn = (wv & 3) * 64;      // 0,64,128,192
    const int lr = lane & 15;
    const int khi = lane >> 4;         // 0..3 -> 16B k-chunk within 64-elem k-step

    // prologue: tile 0 staged and landed
    stageA4(0, 0);
    stageB4(0, 0);
    asm volatile("s_waitcnt vmcnt(0)" ::: "memory");
    __builtin_amdgcn_s_barrier();

    for (int tt = 0; tt < KTILES; tt++) {
        const bool hasNext = (tt + 1 < KTILES);
        const int c = tt & 1, nc = c ^ 1;
        const signed char* Abuf = &lds[c][0];
        const signed char* Bbuf = &lds[c][ABYTES];
#pragma unroll
        for (int p = 0; p < 4; p++) {
            const int ks = p >> 1, mh = p & 1;         // k-step, m-half (compile-time)
            const int kc = ks * 4 + khi;               // 16B chunk index 0..7
            i32x4 av[4], bv[4];
#pragma unroll
            for (int mi = 0; mi < 4; mi++) {
                int row = wm + (mh * 4 + mi) * 16 + lr;
                av[mi] = *(const i32x4*)(Abuf + row * BK + ((kc ^ (row & 7)) << 4));
            }
#pragma unroll
            for (int ni = 0; ni < 4; ni++) {
                int row = wn + ni * 16 + lr;
                bv[ni] = *(const i32x4*)(Bbuf + row * BK + ((kc ^ (row & 7)) << 4));
            }
            if (hasNext) {                              // DMA for tile tt+1 flies across phases
                if (p == 0) stageA4(nc, tt + 1);
                else if (p == 1) stageB4(nc, tt + 1);
            }
            asm volatile("" ::: "memory");
            __builtin_amdgcn_s_barrier();
            asm volatile("s_waitcnt lgkmcnt(0)" ::: "memory");
            __builtin_amdgcn_sched_barrier(0);          // rule #18: MFMA must not hoist
            __builtin_amdgcn_s_setprio(1);
#pragma unroll
            for (int mi = 0; mi < 4; mi++)
#pragma unroll
                for (int ni = 0; ni < 4; ni++)
                    acc[mh * 4 + mi][ni] = __builtin_amdgcn_mfma_i32_16x16x64_i8(
                        av[mi], bv[ni], acc[mh * 4 + mi][ni], 0, 0, 0);
            __builtin_amdgcn_s_setprio(0);
            if (p == 3 && hasNext)                      // next tile's 8 DMAs must have landed
                asm volatile("s_waitcnt vmcnt(0)" ::: "memory");
            asm volatile("" ::: "memory");
            __builtin_amdgcn_s_barrier();
        }
    }

    // epilogue: m = max over this block's cols of sb[col]*dot; atomicMax per row.
    // sa[row] is a positive per-row constant -> applied in k_final (max commutes).
    const int rowbase = mt * BM + wm;
    const int colbase = nt * BN + wn;
    float sbv[4];
#pragma unroll
    for (int ni = 0; ni < 4; ni++) sbv[ni] = sb[colbase + ni * 16 + lr];
#pragma unroll
    for (int mi = 0; mi < 8; mi++) {
#pragma unroll
        for (int j = 0; j < 4; j++) {
            float m = -3.4e38f;
#pragma unroll
            for (int ni = 0; ni < 4; ni++) {
                int col = colbase + ni * 16 + lr;
                if (col < NBANK) m = fmaxf(m, sbv[ni] * (float)acc[mi][ni][j]);
            }
#pragma unroll
            for (int d = 1; d < 16; d <<= 1)   // reduce 16 lanes sharing a C-row
                m = fmaxf(m, __shfl_xor(m, d));
            if (lr == 0) {
                int row = rowbase + mi * 16 + khi * 4 + j;
                if (row < NPATCH) atomicMax(&keys[row], fkey(m));
            }
        }
    }
}

// ---- kernel 4: scores[b] = max_j sqrt(max(2 - 2*sa*keymax, 1e-12)) ----
__global__ void k_final(const unsigned* __restrict__ keys, const float* __restrict__ sa,
                        float* __restrict__ out) {
    int b = threadIdx.x;
    if (b >= 64) return;
    float best = 0.f;
    for (int j = 0; j < 49; j++) {
        int row = b * 49 + j;
        float c = sa[row] * funkey(keys[row]);
        float d2 = fmaxf(2.0f - 2.0f * c, 1e-12f);
        best = fmaxf(best, sqrtf(d2));
    }
    out[b] = best;
}

extern "C" void kernel_launch(void* const* d_in, const int* in_sizes, int n_in,
                              void* d_out, int out_size, void* d_ws, size_t ws_size,
                              hipStream_t stream) {
    const float* tokens = (const float*)d_in[0];   // [64, 50, 768] f32
    const float* mb     = (const float*)d_in[1];   // [100000, 768] f32
    float* out = (float*)d_out;                    // [64] f32

    // ws layout (16B-aligned regions):
    //   Aq i8 [MPAD*DIM] | Bq i8 [NBPAD*DIM] | sa f32[MPAD] | sb f32[NBPAD] | keys u32[MPAD]
    char* ws = (char*)d_ws;
    signed char* Aq = (signed char*)ws;
    signed char* Bq = (signed char*)(ws + (size_t)MPAD * DIM);
    float* sa       = (float*)(ws + (size_t)MPAD * DIM + (size_t)NBPAD * DIM);
    float* sb       = sa + MPAD;
    unsigned* keys  = (unsigned*)(sb + NBPAD);

    k_init <<<(MPAD + 255) / 256, 256, 0, stream>>>(keys);
    k_q8a  <<<MPAD / 4, 256, 0, stream>>>(tokens, Aq, sa);
    k_q8b  <<<NBPAD / 4, 256, 0, stream>>>(mb, Bq, sb);
    k_gemm <<<MT * NT, 512, 0, stream>>>(Aq, Bq, sb, keys);
    k_final<<<1, 64, 0, stream>>>(keys, sa, out);
}